// Round 3
// baseline (2217.717 us; speedup 1.0000x reference)
//
#include <hip/hip_runtime.h>
#include <cmath>
#include <type_traits>

// ChEst: shared-weight Elman RNN, H=8192, 64 steps.
//   U = x @ W_ih^T + b   (f16-MFMA GEMM, written into d_out)
//   h_t = tanh(U[t] + W_hh @ h_{t-1})  via ONE persistent kernel:
//     W_hh f16 resident in VGPRs (192/lane) + LDS (128 KiB/block) across all
//     steps; per-step cost = 16 KiB h broadcast + register dots + grid barrier.
// 256 blocks x 512 thr, 144 KiB dynamic LDS => 1 block/CU, grid == #CUs:
// all blocks co-resident (required for the custom grid barrier).
// d_ws: [0,4K) barrier ctrs | [4K,36K) h double-buf f16 | [64K,64K+1M) x16

#define HDIM 8192
#define NSTEP 64
#define GRID_P 256
#define BLK_P 512      // 8 waves
#define ROWS_B 32      // rows per block (8192/256)
#define R_W 4          // rows per wave (32/8)
#define NCH 16         // 16 chunks of 8 elems = 128 elems/lane/row
#define NCH_REG 12     // chunks held in VGPRs  (4 rows x 12 x 16B = 768B/lane)
#define NCH_LDS 4      // chunks held in LDS    (32 rows x 4 x 1KiB = 128KiB)
#define LDS_BYTES (16384 + 131072)  // h f16[8192] + W_lds

typedef _Float16 f16;
typedef _Float16 f16x2 __attribute__((ext_vector_type(2)));
typedef _Float16 f16x4 __attribute__((ext_vector_type(4)));
typedef _Float16 f16x8 __attribute__((ext_vector_type(8)));
typedef __fp16 fp16x2_raw __attribute__((ext_vector_type(2)));
typedef float f32x4 __attribute__((ext_vector_type(4)));

#if defined(__has_builtin)
#if __has_builtin(__builtin_amdgcn_fdot2)
#define HAS_FDOT2 1
#endif
#endif

__device__ __forceinline__ f16x2 pkrtz(float a, float b) {
  fp16x2_raw r = __builtin_amdgcn_cvt_pkrtz(a, b);
  return __builtin_bit_cast(f16x2, r);
}

__device__ __forceinline__ float dot8(f16x8 a, f16x8 b, float c) {
#ifdef HAS_FDOT2
  f16x2 a0 = {a[0], a[1]}, b0 = {b[0], b[1]};
  f16x2 a1 = {a[2], a[3]}, b1 = {b[2], b[3]};
  f16x2 a2 = {a[4], a[5]}, b2 = {b[4], b[5]};
  f16x2 a3 = {a[6], a[7]}, b3 = {b[6], b[7]};
  c = __builtin_amdgcn_fdot2(a0, b0, c, false);
  c = __builtin_amdgcn_fdot2(a1, b1, c, false);
  c = __builtin_amdgcn_fdot2(a2, b2, c, false);
  c = __builtin_amdgcn_fdot2(a3, b3, c, false);
  return c;
#else
  for (int i = 0; i < 8; i++) c += (float)a[i] * (float)b[i];
  return c;
#endif
}

__device__ __forceinline__ f16x8 cvt8(f32x4 a0, f32x4 a1) {
  f16x2 p0 = pkrtz(a0[0], a0[1]), p1 = pkrtz(a0[2], a0[3]);
  f16x2 p2 = pkrtz(a1[0], a1[1]), p3 = pkrtz(a1[2], a1[3]);
  return (f16x8){p0[0], p0[1], p1[0], p1[1], p2[0], p2[1], p3[0], p3[1]};
}

// ---------------- fp32 -> fp16 convert (for x) -------------------------------
__global__ void cvt_f16_kernel(const float* __restrict__ src,
                               f16* __restrict__ dst, int n4) {
  int idx = blockIdx.x * blockDim.x + threadIdx.x;
  int stride = gridDim.x * blockDim.x;
  for (int i = idx; i < n4; i += stride) {
    f32x4 v = ((const f32x4*)src)[i];
    f16x4 h;
    h[0] = (f16)v[0]; h[1] = (f16)v[1]; h[2] = (f16)v[2]; h[3] = (f16)v[3];
    ((f16x4*)dst)[i] = h;
  }
}

// ---------------- Phase 1: U = x @ W_ih^T + b  (into d_out) ------------------
template <bool XF16>
__global__ __launch_bounds__(256) void gemm_u_kernel(
    const float* __restrict__ x, const f16* __restrict__ x16,
    const float* __restrict__ Wih, const float* __restrict__ b,
    float* __restrict__ out) {
  const int wave = threadIdx.x >> 6;
  const int lane = threadIdx.x & 63;
  const int r = lane & 15, q = lane >> 4;
  const int n0 = blockIdx.x * 16;
  const int m0 = wave * 16;
  const float* wrow = Wih + (size_t)(n0 + r) * HDIM;
  f32x4 acc = {0.f, 0.f, 0.f, 0.f};
#pragma unroll 2
  for (int k0 = 0; k0 < HDIM; k0 += 32) {
    const int kb = k0 + q * 8;
    f16x8 fa;
    if constexpr (XF16) {
      fa = *(const f16x8*)(x16 + (size_t)(m0 + r) * HDIM + kb);
    } else {
      f32x4 a0 = *(const f32x4*)(x + (size_t)(m0 + r) * HDIM + kb);
      f32x4 a1 = *(const f32x4*)(x + (size_t)(m0 + r) * HDIM + kb + 4);
      fa = cvt8(a0, a1);
    }
    f32x4 b0 = *(const f32x4*)(wrow + kb);
    f32x4 b1 = *(const f32x4*)(wrow + kb + 4);
    f16x8 fb = cvt8(b0, b1);
    acc = __builtin_amdgcn_mfma_f32_16x16x32_f16(fa, fb, acc, 0, 0, 0);
  }
  const float bv = b[n0 + r];
#pragma unroll
  for (int i = 0; i < 4; i++) {
    out[(size_t)(m0 + q * 4 + i) * HDIM + n0 + r] = acc[i] + bv;
  }
}

// ---------------- grid barrier (device-scope, hierarchical) ------------------
// bar[g*64] g=0..7: group arrival counters (32 blocks each, 256B apart)
// bar[576]: group-completion counter; bar[640]: generation
__device__ __forceinline__ void gridbar(unsigned* bar, unsigned& my_gen) {
  __syncthreads();
  if (threadIdx.x == 0) {
    __threadfence();  // drain h stores to device scope before arrival
    const unsigned target = my_gen + 1;
    const unsigned g = blockIdx.x & 7u;
    unsigned old = __hip_atomic_fetch_add(&bar[g * 64], 1u, __ATOMIC_ACQ_REL,
                                          __HIP_MEMORY_SCOPE_AGENT);
    if (old == 31u) {
      unsigned o2 = __hip_atomic_fetch_add(&bar[576], 1u, __ATOMIC_ACQ_REL,
                                           __HIP_MEMORY_SCOPE_AGENT);
      if (o2 == 7u) {  // last block of last group: reset, then release
        for (int gg = 0; gg < 8; gg++)
          __hip_atomic_store(&bar[gg * 64], 0u, __ATOMIC_RELAXED,
                             __HIP_MEMORY_SCOPE_AGENT);
        __hip_atomic_store(&bar[576], 0u, __ATOMIC_RELAXED,
                           __HIP_MEMORY_SCOPE_AGENT);
        __hip_atomic_fetch_add(&bar[640], 1u, __ATOMIC_RELEASE,
                               __HIP_MEMORY_SCOPE_AGENT);
      }
    }
    while (__hip_atomic_load(&bar[640], __ATOMIC_ACQUIRE,
                             __HIP_MEMORY_SCOPE_AGENT) < target)
      __builtin_amdgcn_s_sleep(2);
  }
  my_gen++;
  __syncthreads();
}

// ---------------- persistent RNN kernel --------------------------------------
extern __shared__ char smem_dyn[];
__global__ __launch_bounds__(BLK_P, 2) void persist_kernel(
    const float* __restrict__ Whh, float* __restrict__ out,
    f16* __restrict__ hbuf, unsigned* __restrict__ bar) {
  f16* h_lds = (f16*)smem_dyn;            // 16 KiB
  f16* w_lds = (f16*)(smem_dyn + 16384);  // 128 KiB
  const int tid = threadIdx.x;
  const int wave = tid >> 6, lane = tid & 63;
  const int j0 = blockIdx.x * ROWS_B;
  const int jb = j0 + wave * R_W;

  // ---- load W_hh rows for this block: fp32 global -> f16 regs/LDS ----
  f16x8 wreg[R_W][NCH_REG];
#pragma unroll
  for (int r = 0; r < R_W; r++) {
    const float* wrow = Whh + (size_t)(jb + r) * HDIM;
#pragma unroll
    for (int c = 0; c < NCH; c++) {
      const int k = c * 512 + lane * 8;
      f32x4 a0 = *(const f32x4*)(wrow + k);
      f32x4 a1 = *(const f32x4*)(wrow + k + 4);
      f16x8 w8 = cvt8(a0, a1);
      if (c < NCH_REG) {
        wreg[r][c] = w8;
      } else {
        const int row_l = wave * R_W + r;
        *(f16x8*)(w_lds + ((size_t)(row_l * NCH_LDS + (c - NCH_REG)) * 64 + lane) * 8) = w8;
      }
    }
  }

  unsigned my_gen = 0;

  // ---- t = 0: h_0 = tanh(U[0]) ----
  if (tid < ROWS_B) {
    const int j = j0 + tid;
    float v = tanhf(out[j]);
    out[j] = v;
    hbuf[j] = (f16)v;  // half 0
  }
  gridbar(bar, my_gen);

  // ---- t = 1..63 ----
  for (int t = 1; t < NSTEP; t++) {
    const f16* hprev = hbuf + ((t - 1) & 1) * HDIM;
    // stage h_{t-1} (16 KiB) to LDS, coalesced
#pragma unroll
    for (int i = 0; i < HDIM / 8 / BLK_P; i++) {  // 2 iters
      const int idx = i * BLK_P + tid;
      ((f16x8*)h_lds)[idx] = ((const f16x8*)hprev)[idx];
    }
    __syncthreads();

    // prefetch U[t] for my rows (lane 0 only; consumed after reduction)
    float u[R_W];
    if (lane == 0) {
#pragma unroll
      for (int r = 0; r < R_W; r++) u[r] = out[(size_t)t * HDIM + jb + r];
    }

    float acc[R_W] = {0.f, 0.f, 0.f, 0.f};
#pragma unroll
    for (int c = 0; c < NCH_REG; c++) {
      f16x8 hx = *(const f16x8*)(h_lds + c * 512 + lane * 8);
#pragma unroll
      for (int r = 0; r < R_W; r++) acc[r] = dot8(wreg[r][c], hx, acc[r]);
    }
#pragma unroll
    for (int cc = 0; cc < NCH_LDS; cc++) {
      f16x8 hx = *(const f16x8*)(h_lds + (NCH_REG + cc) * 512 + lane * 8);
#pragma unroll
      for (int r = 0; r < R_W; r++) {
        const int row_l = wave * R_W + r;
        f16x8 wl = *(const f16x8*)(w_lds + ((size_t)(row_l * NCH_LDS + cc) * 64 + lane) * 8);
        acc[r] = dot8(wl, hx, acc[r]);
      }
    }

    // reduce each acc over 64 lanes
#pragma unroll
    for (int off = 32; off >= 1; off >>= 1) {
      acc[0] += __shfl_down(acc[0], off, 64);
      acc[1] += __shfl_down(acc[1], off, 64);
      acc[2] += __shfl_down(acc[2], off, 64);
      acc[3] += __shfl_down(acc[3], off, 64);
    }
    if (lane == 0) {
      f16* hcur = hbuf + (t & 1) * HDIM;
#pragma unroll
      for (int r = 0; r < R_W; r++) {
        float v = tanhf(u[r] + acc[r]);
        out[(size_t)t * HDIM + jb + r] = v;
        hcur[jb + r] = (f16)v;
      }
    }
    if (t < NSTEP - 1) gridbar(bar, my_gen);
  }
}

// ---------------- fallback (tiny ws): fp32 step kernels ----------------------
__global__ void step0_kernel(float* __restrict__ out) {
  int i = blockIdx.x * blockDim.x + threadIdx.x;
  out[i] = tanhf(out[i]);
}

__global__ __launch_bounds__(1024) void step_kernel_f32(
    const float* __restrict__ W, float* __restrict__ out, int t) {
  __shared__ float hs[HDIM];
  const float* hprev = out + (size_t)(t - 1) * HDIM;
  {
    const f32x4* hp4 = (const f32x4*)hprev;
#pragma unroll
    for (int i = 0; i < HDIM / 4 / 1024; i++) {
      const int idx = i * 1024 + threadIdx.x;
      *(f32x4*)&hs[idx * 4] = hp4[idx];
    }
  }
  __syncthreads();
  const int wave = threadIdx.x >> 6, lane = threadIdx.x & 63;
  const int j = blockIdx.x * 16 + wave;
  const float* wrow = W + (size_t)j * HDIM;
  float acc = 0.f;
#pragma unroll 4
  for (int it = 0; it < 16; it++) {
    const int kb = it * 512 + lane * 8;
    f32x4 w0 = *(const f32x4*)(wrow + kb);
    f32x4 w1 = *(const f32x4*)(wrow + kb + 4);
    const float* hp = &hs[kb];
    acc += w0[0] * hp[0] + w0[1] * hp[1] + w0[2] * hp[2] + w0[3] * hp[3];
    acc += w1[0] * hp[4] + w1[1] * hp[5] + w1[2] * hp[6] + w1[3] * hp[7];
  }
#pragma unroll
  for (int off = 32; off >= 1; off >>= 1) acc += __shfl_down(acc, off, 64);
  if (lane == 0) {
    const float u = out[(size_t)t * HDIM + j];
    out[(size_t)t * HDIM + j] = tanhf(u + acc);
  }
}

// -----------------------------------------------------------------------------
extern "C" void kernel_launch(void* const* d_in, const int* in_sizes, int n_in,
                              void* d_out, int out_size, void* d_ws,
                              size_t ws_size, hipStream_t stream) {
  const float* x = (const float*)d_in[0];
  const float* Wih = (const float*)d_in[1];
  const float* Whh = (const float*)d_in[2];
  const float* b = (const float*)d_in[3];
  float* out = (float*)d_out;

  const size_t need = 65536 + (size_t)NSTEP * HDIM * sizeof(f16);  // ~1.1 MiB
  if (ws_size >= need) {
    unsigned* bar = (unsigned*)d_ws;
    f16* hbuf = (f16*)((char*)d_ws + 4096);
    f16* x16 = (f16*)((char*)d_ws + 65536);
    hipMemsetAsync(d_ws, 0, 4096, stream);  // barrier ctrs + generation = 0
    cvt_f16_kernel<<<64, 256, 0, stream>>>(x, x16, NSTEP * HDIM / 4);
    gemm_u_kernel<true><<<HDIM / 16, 256, 0, stream>>>(x, x16, Wih, b, out);
    // allow >64KiB dynamic LDS (idempotent; harmless if already set)
    hipFuncSetAttribute((const void*)persist_kernel,
                        hipFuncAttributeMaxDynamicSharedMemorySize, LDS_BYTES);
    persist_kernel<<<GRID_P, BLK_P, LDS_BYTES, stream>>>(Whh, out, hbuf, bar);
  } else {
    gemm_u_kernel<false><<<HDIM / 16, 256, 0, stream>>>(x, nullptr, Wih, b, out);
    step0_kernel<<<HDIM / 256, 256, 0, stream>>>(out);
    for (int t = 1; t < NSTEP; t++)
      step_kernel_f32<<<HDIM / 16, 1024, 0, stream>>>(Whh, out, t);
  }
}